// Round 6
// baseline (151.439 us; speedup 1.0000x reference)
//
#include <hip/hip_runtime.h>
#include <math.h>

#define BATCH 8
#define SEQ   4096
#define DM    128
#define DS    128
#define N2    4096   // complex FFT length (r2c half-size; conv length 8192)
#define NT    256
#define NTP   256

__device__ __forceinline__ float2 cmulf(float2 a, float2 b) {
    return make_float2(a.x * b.x - a.y * b.y, a.x * b.y + a.y * b.x);
}
__device__ __forceinline__ float2 caddf(float2 a, float2 b) { return make_float2(a.x + b.x, a.y + b.y); }
__device__ __forceinline__ float2 csubf(float2 a, float2 b) { return make_float2(a.x - b.x, a.y - b.y); }
__device__ __forceinline__ float2 conjf2(float2 a) { return make_float2(a.x, -a.y); }
__device__ __forceinline__ float2 cisf(float t) { float s, c; __sincosf(t, &s, &c); return make_float2(c, s); }

// nibble-reverse of 12-bit index: bin k sits at position nibrev(k) after 3 radix-16 DIF passes
__device__ __forceinline__ int nibrev(int k) { return ((k & 15) << 8) | (k & 0xF0) | (k >> 8); }
// LDS anti-conflict swizzle (bijection)
__device__ __forceinline__ int physi(int a) { return a ^ ((a >> 4) & 15); }

// ---------------- in-register DFT-16 (verified R4) ----------------
// forward: X[k] = sum_r x[r] W16^{-rk}; output Xh with X[k] = Xh[sig(k)], sig(k)=((k&3)<<2)|(k>>2)
__device__ __forceinline__ void dft16_fwd(const float2 x[16], float2 Xh[16]) {
    const float2 W[10] = { {1.f,0.f},
        {0.92387953f,-0.38268343f},{0.70710678f,-0.70710678f},{0.38268343f,-0.92387953f},
        {0.f,-1.f},{-0.38268343f,-0.92387953f},{-0.70710678f,-0.70710678f},
        {-0.92387953f,-0.38268343f},{-1.f,0.f},{-0.92387953f,0.38268343f} };
    float2 y[16];
#pragma unroll
    for (int j = 0; j < 4; ++j) {
        float2 a0 = x[j], a1 = x[j+4], a2 = x[j+8], a3 = x[j+12];
        float2 t0 = caddf(a0,a2), t1 = csubf(a0,a2);
        float2 t2 = caddf(a1,a3), t3 = csubf(a1,a3);
        float2 b1 = make_float2(t1.x + t3.y, t1.y - t3.x);   // t1 - i t3
        float2 b3 = make_float2(t1.x - t3.y, t1.y + t3.x);   // t1 + i t3
        y[j]    = caddf(t0,t2);
        y[j+4]  = cmulf(b1, W[j]);
        y[j+8]  = cmulf(csubf(t0,t2), W[2*j]);
        y[j+12] = cmulf(b3, W[3*j]);
    }
#pragma unroll
    for (int g = 0; g < 4; ++g) {
        float2 a0 = y[4*g], a1 = y[4*g+1], a2 = y[4*g+2], a3 = y[4*g+3];
        float2 t0 = caddf(a0,a2), t1 = csubf(a0,a2);
        float2 t2 = caddf(a1,a3), t3 = csubf(a1,a3);
        Xh[4*g]   = caddf(t0,t2);
        Xh[4*g+1] = make_float2(t1.x + t3.y, t1.y - t3.x);
        Xh[4*g+2] = csubf(t0,t2);
        Xh[4*g+3] = make_float2(t1.x - t3.y, t1.y + t3.x);
    }
}
__device__ __forceinline__ void dft16_inv(const float2 x[16], float2 Xh[16]) {
    const float2 W[10] = { {1.f,0.f},
        {0.92387953f,0.38268343f},{0.70710678f,0.70710678f},{0.38268343f,0.92387953f},
        {0.f,1.f},{-0.38268343f,0.92387953f},{-0.70710678f,0.70710678f},
        {-0.92387953f,0.38268343f},{-1.f,0.f},{-0.92387953f,-0.38268343f} };
    float2 y[16];
#pragma unroll
    for (int j = 0; j < 4; ++j) {
        float2 a0 = x[j], a1 = x[j+4], a2 = x[j+8], a3 = x[j+12];
        float2 t0 = caddf(a0,a2), t1 = csubf(a0,a2);
        float2 t2 = caddf(a1,a3), t3 = csubf(a1,a3);
        float2 b1 = make_float2(t1.x - t3.y, t1.y + t3.x);   // t1 + i t3
        float2 b3 = make_float2(t1.x + t3.y, t1.y - t3.x);   // t1 - i t3
        y[j]    = caddf(t0,t2);
        y[j+4]  = cmulf(b1, W[j]);
        y[j+8]  = cmulf(csubf(t0,t2), W[2*j]);
        y[j+12] = cmulf(b3, W[3*j]);
    }
#pragma unroll
    for (int g = 0; g < 4; ++g) {
        float2 a0 = y[4*g], a1 = y[4*g+1], a2 = y[4*g+2], a3 = y[4*g+3];
        float2 t0 = caddf(a0,a2), t1 = csubf(a0,a2);
        float2 t2 = caddf(a1,a3), t3 = csubf(a1,a3);
        Xh[4*g]   = caddf(t0,t2);
        Xh[4*g+1] = make_float2(t1.x - t3.y, t1.y + t3.x);
        Xh[4*g+2] = csubf(t0,t2);
        Xh[4*g+3] = make_float2(t1.x + t3.y, t1.y - t3.x);
    }
}

// ---------------- radix-16 LDS stages (swizzled addressing; verified R4) ----------------

template<int Q>
__device__ __forceinline__ void stage_fwd(float2* z, int t) {
    float2 x[16], Xh[16];
    int adr[16];
    if (Q == 16) {
        int j = t & 15, top = t >> 4;
#pragma unroll
        for (int r = 0; r < 16; ++r) adr[r] = (top << 8) + (r << 4) + (j ^ r);
    } else { // Q == 1
        int j4 = t & 15;
#pragma unroll
        for (int r = 0; r < 16; ++r) adr[r] = (t << 4) + (j4 ^ r);
    }
#pragma unroll
    for (int r = 0; r < 16; ++r) x[r] = z[adr[r]];
    dft16_fwd(x, Xh);
    if (Q > 1) {
        int j = t & (Q - 1);
        float2 w1 = cisf(-(float)M_PI / (8.0f * (float)Q) * (float)j);
        float2 w = make_float2(1.f, 0.f);
#pragma unroll
        for (int k = 0; k < 16; ++k) {
            int sk = ((k & 3) << 2) | (k >> 2);
            z[adr[k]] = cmulf(Xh[sk], w);
            w = cmulf(w, w1);
        }
    } else {
#pragma unroll
        for (int k = 0; k < 16; ++k) {
            int sk = ((k & 3) << 2) | (k >> 2);
            z[adr[k]] = Xh[sk];
        }
    }
}

template<int Q>
__device__ __forceinline__ void stage_inv(float2* z, int t) {
    float2 x[16], Xh[16];
    int adr[16];
    if (Q == 16) {
        int j = t & 15, top = t >> 4;
#pragma unroll
        for (int r = 0; r < 16; ++r) adr[r] = (top << 8) + (r << 4) + (j ^ r);
    } else {
        int j4 = t & 15;
#pragma unroll
        for (int r = 0; r < 16; ++r) adr[r] = (t << 4) + (j4 ^ r);
    }
    if (Q > 1) {
        int j = t & (Q - 1);
        float2 w1 = cisf((float)M_PI / (8.0f * (float)Q) * (float)j);
        float2 w = make_float2(1.f, 0.f);
#pragma unroll
        for (int k = 0; k < 16; ++k) {
            x[k] = cmulf(z[adr[k]], w);
            w = cmulf(w, w1);
        }
    } else {
#pragma unroll
        for (int k = 0; k < 16; ++k) x[k] = z[adr[k]];
    }
    dft16_inv(x, Xh);
#pragma unroll
    for (int r = 0; r < 16; ++r) {
        int sr = ((r & 3) << 2) | (r >> 2);
        z[adr[r]] = Xh[sr];
    }
}

// fused global-load + first forward stage (Q=256); input row has 2048 valid float2, rest zero
__device__ __forceinline__ void fwd_first(float2* z, const float2* __restrict__ vrow, int t) {
    float2 x[16], Xh[16];
#pragma unroll
    for (int r = 0; r < 8; ++r) x[r] = vrow[t + (r << 8)];
#pragma unroll
    for (int r = 8; r < 16; ++r) x[r] = make_float2(0.f, 0.f);
    dft16_fwd(x, Xh);
    int b0 = t ^ ((t >> 4) & 15);
    float2 w1 = cisf(-(float)M_PI / 2048.0f * (float)t);
    float2 w = make_float2(1.f, 0.f);
#pragma unroll
    for (int k = 0; k < 16; ++k) {
        int sk = ((k & 3) << 2) | (k >> 2);
        z[b0 + (k << 8)] = cmulf(Xh[sk], w);
        w = cmulf(w, w1);
    }
}

// fused last inverse stage (Q=256) + normalize + skip + store (only outputs n<2048 needed)
__device__ __forceinline__ void inv_last_store(const float2* z, float2* __restrict__ xrow,
                                               int t, float dv) {
    float2 x[16], Xh[16];
    int b0 = t ^ ((t >> 4) & 15);
    float2 w1 = cisf((float)M_PI / 2048.0f * (float)t);
    float2 w = make_float2(1.f, 0.f);
#pragma unroll
    for (int k = 0; k < 16; ++k) {
        x[k] = cmulf(z[b0 + (k << 8)], w);
        w = cmulf(w, w1);
    }
    dft16_inv(x, Xh);
    const float invN = 1.0f / 4096.0f;
#pragma unroll
    for (int r = 0; r < 8; ++r) {
        int sr = ((r & 3) << 2) | (r >> 2);
        float2 res = Xh[sr];
        float2 xv = xrow[t + (r << 8)];
        xrow[t + (r << 8)] = make_float2(res.x * invN + dv * xv.x, res.y * invN + dv * xv.y);
    }
}

// ---------------- P/Q pair coefficients (validated R3/R4; verbatim) ----------------
__device__ __forceinline__ void pq_one(float2 Kk, float2 Kkp, float thk,
                                       float2 fap, float2 fbp,
                                       float2* P, float2* Q) {
    float2 e  = cisf(-thk);
    float2 fa = make_float2(0.5f * (1.f + e.y), -0.5f * e.x);
    float2 fb = make_float2(0.5f * (1.f - e.y),  0.5f * e.x);
    float2 ak = cmulf(Kk, fa), bk = cmulf(Kk, fb);
    float2 apv = cmulf(Kkp, fap), bpv = cmulf(Kkp, fbp);
    float2 g = make_float2(0.5f * (1.f + e.y), 0.5f * e.x);
    float2 h = make_float2(0.5f * (1.f - e.y), -0.5f * e.x);
    *P = caddf(cmulf(g, ak), cmulf(h, conjf2(bpv)));
    *Q = caddf(cmulf(g, bk), cmulf(h, conjf2(apv)));
}
__device__ __forceinline__ void pq_pair(float2 Kk, float2 Kkp, float thk, float thkp,
                                        float2* Pk, float2* Qk, float2* Pkp, float2* Qkp) {
    float2 e  = cisf(-thk);
    float2 ep = cisf(-thkp);
    float2 fa  = make_float2(0.5f * (1.f + e.y),  -0.5f * e.x);
    float2 fb  = make_float2(0.5f * (1.f - e.y),   0.5f * e.x);
    float2 fap = make_float2(0.5f * (1.f + ep.y), -0.5f * ep.x);
    float2 fbp = make_float2(0.5f * (1.f - ep.y),  0.5f * ep.x);
    pq_one(Kk,  Kkp, thk,  fap, fbp, Pk,  Qk);
    pq_one(Kkp, Kk,  thkp, fa,  fb,  Pkp, Qkp);
}

// ---------------- fused prep: transpose_xin (blocks 0..4095) || psum (4096..4351) || G (4352..4415)
__global__ void __launch_bounds__(NTP) prep_fused(
    const float* __restrict__ x, float* __restrict__ xt,
    const float* __restrict__ Lam, const float* __restrict__ logdt, float* __restrict__ Psum,
    const float* __restrict__ Cm, const float* __restrict__ Bm, float* __restrict__ GT) {
    int bid = blockIdx.x, t = threadIdx.x;
    if (bid < 4096) {
        __shared__ float tile[32][33];
        int l0 = (bid & 127) * 32, m0 = ((bid >> 7) & 3) * 32, b = bid >> 9;
        int tx = t & 31, ty = t >> 5;
#pragma unroll
        for (int r = 0; r < 4; ++r) {
            int l = l0 + ty + r * 8;
            tile[ty + r * 8][tx] = x[(size_t)b * SEQ * DM + (size_t)l * DM + m0 + tx];
        }
        __syncthreads();
#pragma unroll
        for (int r = 0; r < 4; ++r) {
            int m = m0 + ty + r * 8;
            xt[(size_t)b * DM * SEQ + (size_t)m * SEQ + l0 + tx] = tile[tx][ty + r * 8];
        }
    } else if (bid < 4352) {
        __shared__ float E[DM];
        int sb = bid - 4096;
        int s = sb >> 1, half = sb & 1;
        if (t < DM) E[t] = __expf(logdt[t]) * Lam[s];
        __syncthreads();
        int l0 = t + 2048 * half;
        float acc[8] = {0.f,0.f,0.f,0.f,0.f,0.f,0.f,0.f};
        for (int m = 0; m < DM; ++m) {
            float e = E[m];
            float w = __expf(e * (float)l0);
            float r = __expf(e * 256.0f);
#pragma unroll
            for (int i = 0; i < 8; ++i) { acc[i] += w; w *= r; }
        }
#pragma unroll
        for (int i = 0; i < 8; ++i) Psum[s * SEQ + l0 + 256 * i] = acc[i];
    } else {
        int gid = (bid - 4352) * NTP + t;
        int m = gid >> 7, j = gid & 127;
        float acc = 0.f;
        for (int i = 0; i < DS; ++i) acc += Cm[m * DS + i] * Bm[i * DM + j];
        GT[j * DM + m] = acc;   // transposed for prep_K2
    }
}

// K[m,l] = sum_s GT[s,m]*Psum[s,l]; 16-wide l tile staged in LDS once (verified R4)
__global__ void prep_K2(const float* __restrict__ GT, const float* __restrict__ Psum,
                        float* __restrict__ K) {
    __shared__ float4 PT[DS][4];
    int l0 = blockIdx.x * 16;
    int t = threadIdx.x;
    for (int idx = t; idx < 512; idx += NTP) {
        int s = idx >> 2, q = idx & 3;
        PT[s][q] = ((const float4*)(Psum + s * SEQ + l0))[q];
    }
    __syncthreads();
    int m = t & 127, half = t >> 7;
    float acc[8] = {0.f,0.f,0.f,0.f,0.f,0.f,0.f,0.f};
    for (int s = 0; s < DS; ++s) {
        float g = GT[s * DM + m];
        float4 p0 = PT[s][half * 2], p1 = PT[s][half * 2 + 1];
        acc[0] += g * p0.x; acc[1] += g * p0.y; acc[2] += g * p0.z; acc[3] += g * p0.w;
        acc[4] += g * p1.x; acc[5] += g * p1.y; acc[6] += g * p1.z; acc[7] += g * p1.w;
    }
    float4* kp = (float4*)(K + (size_t)m * SEQ + l0 + half * 8);
    kp[0] = make_float4(acc[0], acc[1], acc[2], acc[3]);
    kp[1] = make_float4(acc[4], acc[5], acc[6], acc[7]);
}

// ---------------- fused: FFT of K row + Hermitian unpack + P/Q build (verified R4) ----------------
__global__ void __launch_bounds__(NT, 4) fftK_PQ(const float* __restrict__ K,
                                                 float4* __restrict__ PQ) {
    __shared__ __align__(16) float2 z[N2];
    int t = threadIdx.x, m = blockIdx.x;
    const float2* krow = (const float2*)(K + (size_t)m * SEQ);

    fwd_first(z, krow, t);  __syncthreads();
    stage_fwd<16>(z, t);    __syncthreads();
    stage_fwd<1>(z, t);     __syncthreads();

    float4* dst = PQ + (size_t)m * 4096;
#pragma unroll
    for (int c = 0; c < 8; ++c) {
        int k = t + 256 * c;
        float2 Pk, Qk, Pkp, Qkp;
        if (k == 0) {
            float2 v0 = z[0];                       // physi(0)=0
            float2 v2 = z[8];                       // pos(2048)=8, physi(8)=8
            float2 Ku0    = make_float2(v0.x + v0.y, 0.f);
            float2 Ku4096 = make_float2(v0.x - v0.y, 0.f);
            float2 Ku2048 = conjf2(v2);
            float2 Pd, Qd;
            pq_pair(Ku0, Ku4096, 0.f, (float)M_PI, &Pk, &Qk, &Pd, &Qd);
            float th2 = 0.5f * (float)M_PI;
            pq_pair(Ku2048, Ku2048, th2, th2, &Pkp, &Qkp, &Pd, &Qd);
        } else {
            int kp = 4096 - k;
            float2 va = z[physi(nibrev(k))];
            float2 vb = z[physi(nibrev(kp))];
            float thk  = (float)M_PI * (float)k / 4096.0f;
            float thkp = (float)M_PI - thk;
            float2 e  = cisf(-thk);
            float2 cb = conjf2(vb);
            float2 s  = caddf(va, cb), d = csubf(va, cb);
            float2 pr = cmulf(e, d);
            float2 Kuk = make_float2(0.5f * (s.x + pr.y), 0.5f * (s.y - pr.x));
            float2 ep = make_float2(-e.x, e.y);
            float2 ca = conjf2(va);
            float2 s2 = caddf(vb, ca), d2 = csubf(vb, ca);
            float2 p2 = cmulf(ep, d2);
            float2 Kukp = make_float2(0.5f * (s2.x + p2.y), 0.5f * (s2.y - p2.x));
            pq_pair(Kuk, Kukp, thk, thkp, &Pk, &Qk, &Pkp, &Qkp);
        }
        dst[2 * k]     = make_float4(Pk.x, Pk.y, Qk.x, Qk.y);
        dst[2 * k + 1] = make_float4(Pkp.x, Pkp.y, Qkp.x, Qkp.y);
    }
}

// ---------------- main convolution (radix-16; verified R4 = best known) ----------------
__global__ void __launch_bounds__(NT, 4) conv16(float* __restrict__ xt,
                                                const float4* __restrict__ PQ,
                                                const float* __restrict__ Dv) {
    __shared__ __align__(16) float2 z[N2];
    int t = threadIdx.x;
    int m = blockIdx.x & (DM - 1);
    int b = blockIdx.x >> 7;
    float2* xrow = (float2*)(xt + (((size_t)b * DM + m) << 12));

    fwd_first(z, xrow, t);  __syncthreads();
    stage_fwd<16>(z, t);    __syncthreads();
    stage_fwd<1>(z, t);     __syncthreads();

    // pointwise in digit-reversed domain: W = P*V + Q*conj(V[partner]); one thread per pair
    {
        const float4* pq = PQ + (size_t)m * 4096;
#pragma unroll
        for (int c = 0; c < 8; ++c) {
            int k = t + 256 * c;
            float4 lo = pq[2 * k];
            float4 hi = pq[2 * k + 1];
            if (k == 0) {
                float2 v0 = z[0];
                z[0] = caddf(cmulf(make_float2(lo.x, lo.y), v0),
                             cmulf(make_float2(lo.z, lo.w), conjf2(v0)));
                float2 v2 = z[8];
                z[8] = caddf(cmulf(make_float2(hi.x, hi.y), v2),
                             cmulf(make_float2(hi.z, hi.w), conjf2(v2)));
            } else {
                int i  = physi(nibrev(k));
                int ip = physi(nibrev(4096 - k));
                float2 va = z[i], vb = z[ip];
                z[i]  = caddf(cmulf(make_float2(lo.x, lo.y), va),
                              cmulf(make_float2(lo.z, lo.w), conjf2(vb)));
                z[ip] = caddf(cmulf(make_float2(hi.x, hi.y), vb),
                              cmulf(make_float2(hi.z, hi.w), conjf2(va)));
            }
        }
    }
    __syncthreads();

    stage_inv<1>(z, t);     __syncthreads();
    stage_inv<16>(z, t);    __syncthreads();
    inv_last_store(z, xrow, t, Dv[m]);
}

// ---------------- output transpose ----------------
__global__ void transpose_yout(const float* __restrict__ yt, float* __restrict__ out) {
    __shared__ float tile[32][33];
    int b = blockIdx.z;
    int l0 = blockIdx.x * 32, m0 = blockIdx.y * 32;
    int tx = threadIdx.x, ty = threadIdx.y;
#pragma unroll
    for (int r = 0; r < 4; ++r) {
        int m = m0 + ty + r * 8;
        tile[ty + r * 8][tx] = yt[(size_t)b * DM * SEQ + (size_t)m * SEQ + l0 + tx];
    }
    __syncthreads();
#pragma unroll
    for (int r = 0; r < 4; ++r) {
        int l = l0 + ty + r * 8;
        out[(size_t)b * SEQ * DM + (size_t)l * DM + m0 + tx] = tile[tx][ty + r * 8];
    }
}

extern "C" void kernel_launch(void* const* d_in, const int* in_sizes, int n_in,
                              void* d_out, int out_size, void* d_ws, size_t ws_size,
                              hipStream_t stream) {
    const float* x     = (const float*)d_in[0];
    const float* Lam   = (const float*)d_in[1];
    const float* Bm    = (const float*)d_in[2];
    const float* Cm    = (const float*)d_in[3];
    const float* Dv    = (const float*)d_in[4];
    const float* logdt = (const float*)d_in[5];
    float* out = (float*)d_out;

    float*  ws   = (float*)d_ws;
    float*  xt   = ws;                                   // 4,194,304 floats (16 MB)
    float4* PQ   = (float4*)(ws + 4194304);              // 128*2048*2 float4 (8 MB)
    float*  K    = ws + 4194304 + 2097152;               // 524,288 floats (2 MB)
    float*  Psum = K + 524288;                           // 524,288 floats (2 MB)
    float*  GT   = Psum + 524288;                        // 16,384 floats

    hipLaunchKernelGGL(prep_fused,     dim3(4416),       dim3(NTP),    0, stream,
                       x, xt, Lam, logdt, Psum, Cm, Bm, GT);
    hipLaunchKernelGGL(prep_K2,        dim3(256),        dim3(NTP),    0, stream, GT, Psum, K);
    hipLaunchKernelGGL(fftK_PQ,        dim3(128),        dim3(NT),     0, stream, K, PQ);
    hipLaunchKernelGGL(conv16,         dim3(1024),       dim3(NT),     0, stream, xt, PQ, Dv);
    hipLaunchKernelGGL(transpose_yout, dim3(128, 4, 8),  dim3(32, 8),  0, stream, xt, out);
}

// Round 7
// 134.824 us; speedup vs baseline: 1.1232x; 1.1232x over previous
//
#include <hip/hip_runtime.h>
#include <math.h>

#define BATCH 8
#define SEQ   4096
#define DM    128
#define DS    128
#define N2    4096   // complex FFT length (r2c half-size; conv length 8192)
#define NT    256
#define NTP   256

__device__ __forceinline__ float2 cmulf(float2 a, float2 b) {
    return make_float2(a.x * b.x - a.y * b.y, a.x * b.y + a.y * b.x);
}
__device__ __forceinline__ float2 caddf(float2 a, float2 b) { return make_float2(a.x + b.x, a.y + b.y); }
__device__ __forceinline__ float2 csubf(float2 a, float2 b) { return make_float2(a.x - b.x, a.y - b.y); }
__device__ __forceinline__ float2 conjf2(float2 a) { return make_float2(a.x, -a.y); }
__device__ __forceinline__ float2 cisf(float t) { float s, c; __sincosf(t, &s, &c); return make_float2(c, s); }

// nibble-reverse of 12-bit index (involution): bin k sits at logical position nibrev(k)
__device__ __forceinline__ int nibrev(int k) { return ((k & 15) << 8) | (k & 0xF0) | (k >> 8); }
// LDS anti-conflict swizzle (involutive bijection)
__device__ __forceinline__ int physi(int a) { return a ^ ((a >> 4) & 15); }

// ---------------- in-register DFT-16 (verified R4) ----------------
__device__ __forceinline__ void dft16_fwd(const float2 x[16], float2 Xh[16]) {
    const float2 W[10] = { {1.f,0.f},
        {0.92387953f,-0.38268343f},{0.70710678f,-0.70710678f},{0.38268343f,-0.92387953f},
        {0.f,-1.f},{-0.38268343f,-0.92387953f},{-0.70710678f,-0.70710678f},
        {-0.92387953f,-0.38268343f},{-1.f,0.f},{-0.92387953f,0.38268343f} };
    float2 y[16];
#pragma unroll
    for (int j = 0; j < 4; ++j) {
        float2 a0 = x[j], a1 = x[j+4], a2 = x[j+8], a3 = x[j+12];
        float2 t0 = caddf(a0,a2), t1 = csubf(a0,a2);
        float2 t2 = caddf(a1,a3), t3 = csubf(a1,a3);
        float2 b1 = make_float2(t1.x + t3.y, t1.y - t3.x);
        float2 b3 = make_float2(t1.x - t3.y, t1.y + t3.x);
        y[j]    = caddf(t0,t2);
        y[j+4]  = cmulf(b1, W[j]);
        y[j+8]  = cmulf(csubf(t0,t2), W[2*j]);
        y[j+12] = cmulf(b3, W[3*j]);
    }
#pragma unroll
    for (int g = 0; g < 4; ++g) {
        float2 a0 = y[4*g], a1 = y[4*g+1], a2 = y[4*g+2], a3 = y[4*g+3];
        float2 t0 = caddf(a0,a2), t1 = csubf(a0,a2);
        float2 t2 = caddf(a1,a3), t3 = csubf(a1,a3);
        Xh[4*g]   = caddf(t0,t2);
        Xh[4*g+1] = make_float2(t1.x + t3.y, t1.y - t3.x);
        Xh[4*g+2] = csubf(t0,t2);
        Xh[4*g+3] = make_float2(t1.x - t3.y, t1.y + t3.x);
    }
}
__device__ __forceinline__ void dft16_inv(const float2 x[16], float2 Xh[16]) {
    const float2 W[10] = { {1.f,0.f},
        {0.92387953f,0.38268343f},{0.70710678f,0.70710678f},{0.38268343f,0.92387953f},
        {0.f,1.f},{-0.38268343f,0.92387953f},{-0.70710678f,0.70710678f},
        {-0.92387953f,0.38268343f},{-1.f,0.f},{-0.92387953f,-0.38268343f} };
    float2 y[16];
#pragma unroll
    for (int j = 0; j < 4; ++j) {
        float2 a0 = x[j], a1 = x[j+4], a2 = x[j+8], a3 = x[j+12];
        float2 t0 = caddf(a0,a2), t1 = csubf(a0,a2);
        float2 t2 = caddf(a1,a3), t3 = csubf(a1,a3);
        float2 b1 = make_float2(t1.x - t3.y, t1.y + t3.x);
        float2 b3 = make_float2(t1.x + t3.y, t1.y - t3.x);
        y[j]    = caddf(t0,t2);
        y[j+4]  = cmulf(b1, W[j]);
        y[j+8]  = cmulf(csubf(t0,t2), W[2*j]);
        y[j+12] = cmulf(b3, W[3*j]);
    }
#pragma unroll
    for (int g = 0; g < 4; ++g) {
        float2 a0 = y[4*g], a1 = y[4*g+1], a2 = y[4*g+2], a3 = y[4*g+3];
        float2 t0 = caddf(a0,a2), t1 = csubf(a0,a2);
        float2 t2 = caddf(a1,a3), t3 = csubf(a1,a3);
        Xh[4*g]   = caddf(t0,t2);
        Xh[4*g+1] = make_float2(t1.x - t3.y, t1.y + t3.x);
        Xh[4*g+2] = csubf(t0,t2);
        Xh[4*g+3] = make_float2(t1.x + t3.y, t1.y - t3.x);
    }
}

// ---------------- radix-16 LDS stages (verified R4; unchanged) ----------------

template<int Q>
__device__ __forceinline__ void stage_fwd(float2* z, int t) {
    float2 x[16], Xh[16];
    int adr[16];
    if (Q == 16) {
        int j = t & 15, top = t >> 4;
#pragma unroll
        for (int r = 0; r < 16; ++r) adr[r] = (top << 8) + (r << 4) + (j ^ r);
    } else { // Q == 1
        int j4 = t & 15;
#pragma unroll
        for (int r = 0; r < 16; ++r) adr[r] = (t << 4) + (j4 ^ r);
    }
#pragma unroll
    for (int r = 0; r < 16; ++r) x[r] = z[adr[r]];
    dft16_fwd(x, Xh);
    if (Q > 1) {
        int j = t & (Q - 1);
        float2 w1 = cisf(-(float)M_PI / (8.0f * (float)Q) * (float)j);
        float2 w = make_float2(1.f, 0.f);
#pragma unroll
        for (int k = 0; k < 16; ++k) {
            int sk = ((k & 3) << 2) | (k >> 2);
            z[adr[k]] = cmulf(Xh[sk], w);
            w = cmulf(w, w1);
        }
    } else {
#pragma unroll
        for (int k = 0; k < 16; ++k) {
            int sk = ((k & 3) << 2) | (k >> 2);
            z[adr[k]] = Xh[sk];
        }
    }
}

template<int Q>
__device__ __forceinline__ void stage_inv(float2* z, int t) {
    float2 x[16], Xh[16];
    int adr[16];
    if (Q == 16) {
        int j = t & 15, top = t >> 4;
#pragma unroll
        for (int r = 0; r < 16; ++r) adr[r] = (top << 8) + (r << 4) + (j ^ r);
    } else {
        int j4 = t & 15;
#pragma unroll
        for (int r = 0; r < 16; ++r) adr[r] = (t << 4) + (j4 ^ r);
    }
    if (Q > 1) {
        int j = t & (Q - 1);
        float2 w1 = cisf((float)M_PI / (8.0f * (float)Q) * (float)j);
        float2 w = make_float2(1.f, 0.f);
#pragma unroll
        for (int k = 0; k < 16; ++k) {
            x[k] = cmulf(z[adr[k]], w);
            w = cmulf(w, w1);
        }
    } else {
#pragma unroll
        for (int k = 0; k < 16; ++k) x[k] = z[adr[k]];
    }
    dft16_inv(x, Xh);
#pragma unroll
    for (int r = 0; r < 16; ++r) {
        int sr = ((r & 3) << 2) | (r >> 2);
        z[adr[r]] = Xh[sr];
    }
}

__device__ __forceinline__ void fwd_first(float2* z, const float2* __restrict__ vrow, int t) {
    float2 x[16], Xh[16];
#pragma unroll
    for (int r = 0; r < 8; ++r) x[r] = vrow[t + (r << 8)];
#pragma unroll
    for (int r = 8; r < 16; ++r) x[r] = make_float2(0.f, 0.f);
    dft16_fwd(x, Xh);
    int b0 = t ^ ((t >> 4) & 15);
    float2 w1 = cisf(-(float)M_PI / 2048.0f * (float)t);
    float2 w = make_float2(1.f, 0.f);
#pragma unroll
    for (int k = 0; k < 16; ++k) {
        int sk = ((k & 3) << 2) | (k >> 2);
        z[b0 + (k << 8)] = cmulf(Xh[sk], w);
        w = cmulf(w, w1);
    }
}

__device__ __forceinline__ void inv_last_store(const float2* z, float2* __restrict__ xrow,
                                               int t, float dv) {
    float2 x[16], Xh[16];
    int b0 = t ^ ((t >> 4) & 15);
    float2 w1 = cisf((float)M_PI / 2048.0f * (float)t);
    float2 w = make_float2(1.f, 0.f);
#pragma unroll
    for (int k = 0; k < 16; ++k) {
        x[k] = cmulf(z[b0 + (k << 8)], w);
        w = cmulf(w, w1);
    }
    dft16_inv(x, Xh);
    const float invN = 1.0f / 4096.0f;
#pragma unroll
    for (int r = 0; r < 8; ++r) {
        int sr = ((r & 3) << 2) | (r >> 2);
        float2 res = Xh[sr];
        float2 xv = xrow[t + (r << 8)];
        xrow[t + (r << 8)] = make_float2(res.x * invN + dv * xv.x, res.y * invN + dv * xv.y);
    }
}

// ---------------- P/Q pair coefficients (validated R3/R4; verbatim) ----------------
__device__ __forceinline__ void pq_one(float2 Kk, float2 Kkp, float thk,
                                       float2 fap, float2 fbp,
                                       float2* P, float2* Q) {
    float2 e  = cisf(-thk);
    float2 fa = make_float2(0.5f * (1.f + e.y), -0.5f * e.x);
    float2 fb = make_float2(0.5f * (1.f - e.y),  0.5f * e.x);
    float2 ak = cmulf(Kk, fa), bk = cmulf(Kk, fb);
    float2 apv = cmulf(Kkp, fap), bpv = cmulf(Kkp, fbp);
    float2 g = make_float2(0.5f * (1.f + e.y), 0.5f * e.x);
    float2 h = make_float2(0.5f * (1.f - e.y), -0.5f * e.x);
    *P = caddf(cmulf(g, ak), cmulf(h, conjf2(bpv)));
    *Q = caddf(cmulf(g, bk), cmulf(h, conjf2(apv)));
}
__device__ __forceinline__ void pq_pair(float2 Kk, float2 Kkp, float thk, float thkp,
                                        float2* Pk, float2* Qk, float2* Pkp, float2* Qkp) {
    float2 e  = cisf(-thk);
    float2 ep = cisf(-thkp);
    float2 fa  = make_float2(0.5f * (1.f + e.y),  -0.5f * e.x);
    float2 fb  = make_float2(0.5f * (1.f - e.y),   0.5f * e.x);
    float2 fap = make_float2(0.5f * (1.f + ep.y), -0.5f * ep.x);
    float2 fbp = make_float2(0.5f * (1.f - ep.y),  0.5f * ep.x);
    pq_one(Kk,  Kkp, thk,  fap, fbp, Pk,  Qk);
    pq_one(Kkp, Kk,  thkp, fa,  fb,  Pkp, Qkp);
}

// ---------------- prep kernels (R4 structure: SEPARATE launches — fused version measured worse) ----------------

__global__ void prep_G(const float* __restrict__ Cm, const float* __restrict__ Bm,
                       float* __restrict__ GT) {
    int gid = blockIdx.x * blockDim.x + threadIdx.x;
    int m = gid >> 7, j = gid & 127;
    float acc = 0.f;
    for (int i = 0; i < DS; ++i) acc += Cm[m * DS + i] * Bm[i * DM + j];
    GT[j * DM + m] = acc;   // transposed for prep_K2
}

__global__ void prep_psum2(const float* __restrict__ Lam, const float* __restrict__ logdt,
                           float* __restrict__ Psum) {
    __shared__ float E[DM];
    int s = blockIdx.x >> 1, half = blockIdx.x & 1;
    int t = threadIdx.x;
    if (t < DM) E[t] = __expf(logdt[t]) * Lam[s];
    __syncthreads();
    int l0 = t + 2048 * half;
    float acc[8] = {0.f,0.f,0.f,0.f,0.f,0.f,0.f,0.f};
    for (int m = 0; m < DM; ++m) {
        float e = E[m];
        float w = __expf(e * (float)l0);
        float r = __expf(e * 256.0f);
#pragma unroll
        for (int i = 0; i < 8; ++i) { acc[i] += w; w *= r; }
    }
#pragma unroll
    for (int i = 0; i < 8; ++i) Psum[s * SEQ + l0 + 256 * i] = acc[i];
}

__global__ void prep_K2(const float* __restrict__ GT, const float* __restrict__ Psum,
                        float* __restrict__ K) {
    __shared__ float4 PT[DS][4];
    int l0 = blockIdx.x * 16;
    int t = threadIdx.x;
    for (int idx = t; idx < 512; idx += NTP) {
        int s = idx >> 2, q = idx & 3;
        PT[s][q] = ((const float4*)(Psum + s * SEQ + l0))[q];
    }
    __syncthreads();
    int m = t & 127, half = t >> 7;
    float acc[8] = {0.f,0.f,0.f,0.f,0.f,0.f,0.f,0.f};
    for (int s = 0; s < DS; ++s) {
        float g = GT[s * DM + m];
        float4 p0 = PT[s][half * 2], p1 = PT[s][half * 2 + 1];
        acc[0] += g * p0.x; acc[1] += g * p0.y; acc[2] += g * p0.z; acc[3] += g * p0.w;
        acc[4] += g * p1.x; acc[5] += g * p1.y; acc[6] += g * p1.z; acc[7] += g * p1.w;
    }
    float4* kp = (float4*)(K + (size_t)m * SEQ + l0 + half * 8);
    kp[0] = make_float4(acc[0], acc[1], acc[2], acc[3]);
    kp[1] = make_float4(acc[4], acc[5], acc[6], acc[7]);
}

// ---------------- fused: FFT of K row + Hermitian unpack + P/Q build ----------------
// Pair enumeration: slot (c,t) -> logical position pos=(t<<4)|c (bit3==0 <=> bin<2048),
// bin k=nibrev(pos). Table index (c<<8)|t -> coalesced. z access low-nibble = c^(t&15) -> 4-way.
__global__ void __launch_bounds__(NT, 4) fftK_PQ(const float* __restrict__ K,
                                                 float4* __restrict__ PQ) {
    __shared__ __align__(16) float2 z[N2];
    int t = threadIdx.x, m = blockIdx.x;
    const float2* krow = (const float2*)(K + (size_t)m * SEQ);

    fwd_first(z, krow, t);  __syncthreads();
    stage_fwd<16>(z, t);    __syncthreads();
    stage_fwd<1>(z, t);     __syncthreads();

    float4* dst = PQ + (size_t)m * 4096;
#pragma unroll
    for (int c = 0; c < 8; ++c) {
        int idx2 = (((c << 8) | t)) << 1;
        int pos = (t << 4) | c;
        float2 Pk, Qk, Pkp, Qkp;
        if (pos == 0) {
            float2 v0 = z[0];                       // bin 0 (physi(0)=0)
            float2 v2 = z[8];                       // bin 2048 at pos 8, physi(8)=8
            float2 Ku0    = make_float2(v0.x + v0.y, 0.f);
            float2 Ku4096 = make_float2(v0.x - v0.y, 0.f);
            float2 Ku2048 = conjf2(v2);
            float2 Pd, Qd;
            pq_pair(Ku0, Ku4096, 0.f, (float)M_PI, &Pk, &Qk, &Pd, &Qd);
            float th2 = 0.5f * (float)M_PI;
            pq_pair(Ku2048, Ku2048, th2, th2, &Pkp, &Qkp, &Pd, &Qd);
        } else {
            int k  = nibrev(pos);                   // 1..2047
            int kp = 4096 - k;
            float2 va = z[physi(pos)];
            float2 vb = z[physi(nibrev(kp))];
            float thk  = (float)M_PI * (float)k / 4096.0f;
            float thkp = (float)M_PI - thk;
            float2 e  = cisf(-thk);
            float2 cb = conjf2(vb);
            float2 s  = caddf(va, cb), d = csubf(va, cb);
            float2 pr = cmulf(e, d);
            float2 Kuk = make_float2(0.5f * (s.x + pr.y), 0.5f * (s.y - pr.x));
            float2 ep = make_float2(-e.x, e.y);
            float2 ca = conjf2(va);
            float2 s2 = caddf(vb, ca), d2 = csubf(vb, ca);
            float2 p2 = cmulf(ep, d2);
            float2 Kukp = make_float2(0.5f * (s2.x + p2.y), 0.5f * (s2.y - p2.x));
            pq_pair(Kuk, Kukp, thk, thkp, &Pk, &Qk, &Pkp, &Qkp);
        }
        dst[idx2]     = make_float4(Pk.x, Pk.y, Qk.x, Qk.y);
        dst[idx2 + 1] = make_float4(Pkp.x, Pkp.y, Qkp.x, Qkp.y);
    }
}

// ---------------- main convolution (radix-16; R4-verified core, re-keyed pointwise) ----------------
__global__ void __launch_bounds__(NT, 4) conv16(float* __restrict__ xt,
                                                const float4* __restrict__ PQ,
                                                const float* __restrict__ Dv) {
    __shared__ __align__(16) float2 z[N2];
    int t = threadIdx.x;
    int m = blockIdx.x & (DM - 1);
    int b = blockIdx.x >> 7;
    float2* xrow = (float2*)(xt + (((size_t)b * DM + m) << 12));

    fwd_first(z, xrow, t);  __syncthreads();
    stage_fwd<16>(z, t);    __syncthreads();
    stage_fwd<1>(z, t);     __syncthreads();

    // pointwise: W = P*V + Q*conj(V[partner]); one thread per pair, no inner barrier
    {
        const float4* pq = PQ + (size_t)m * 4096;
#pragma unroll
        for (int c = 0; c < 8; ++c) {
            int idx2 = (((c << 8) | t)) << 1;
            int pos = (t << 4) | c;
            float4 lo = pq[idx2];
            float4 hi = pq[idx2 + 1];
            if (pos == 0) {
                float2 v0 = z[0];
                z[0] = caddf(cmulf(make_float2(lo.x, lo.y), v0),
                             cmulf(make_float2(lo.z, lo.w), conjf2(v0)));
                float2 v2 = z[8];
                z[8] = caddf(cmulf(make_float2(hi.x, hi.y), v2),
                             cmulf(make_float2(hi.z, hi.w), conjf2(v2)));
            } else {
                int k  = nibrev(pos);
                int i  = physi(pos);
                int ip = physi(nibrev(4096 - k));
                float2 va = z[i], vb = z[ip];
                z[i]  = caddf(cmulf(make_float2(lo.x, lo.y), va),
                              cmulf(make_float2(lo.z, lo.w), conjf2(vb)));
                z[ip] = caddf(cmulf(make_float2(hi.x, hi.y), vb),
                              cmulf(make_float2(hi.z, hi.w), conjf2(va)));
            }
        }
    }
    __syncthreads();

    stage_inv<1>(z, t);     __syncthreads();
    stage_inv<16>(z, t);    __syncthreads();
    inv_last_store(z, xrow, t, Dv[m]);
}

// ---------------- float4 transposes ----------------
// x (B,L,M) -> xt (B,M,L); 32x32 tile, one float4 global op per thread per phase
__global__ void transpose_xin(const float* __restrict__ x, float* __restrict__ xt) {
    __shared__ float tile[32][33];
    int b = blockIdx.z;
    int l0 = blockIdx.x * 32, m0 = blockIdx.y * 32;
    int t = threadIdx.x;
    int lr = t >> 3, mc4 = (t & 7) * 4;
    float4 v = *(const float4*)&x[(size_t)b * SEQ * DM + (size_t)(l0 + lr) * DM + m0 + mc4];
    tile[lr][mc4 + 0] = v.x; tile[lr][mc4 + 1] = v.y;
    tile[lr][mc4 + 2] = v.z; tile[lr][mc4 + 3] = v.w;
    __syncthreads();
    int mr = t >> 3, lc4 = (t & 7) * 4;
    float4 o = make_float4(tile[lc4 + 0][mr], tile[lc4 + 1][mr],
                           tile[lc4 + 2][mr], tile[lc4 + 3][mr]);
    *(float4*)&xt[(size_t)b * DM * SEQ + (size_t)(m0 + mr) * SEQ + l0 + lc4] = o;
}

// yt (B,M,L) -> out (B,L,M)
__global__ void transpose_yout(const float* __restrict__ yt, float* __restrict__ out) {
    __shared__ float tile[32][33];
    int b = blockIdx.z;
    int l0 = blockIdx.x * 32, m0 = blockIdx.y * 32;
    int t = threadIdx.x;
    int mr = t >> 3, lc4 = (t & 7) * 4;
    float4 v = *(const float4*)&yt[(size_t)b * DM * SEQ + (size_t)(m0 + mr) * SEQ + l0 + lc4];
    tile[mr][lc4 + 0] = v.x; tile[mr][lc4 + 1] = v.y;
    tile[mr][lc4 + 2] = v.z; tile[mr][lc4 + 3] = v.w;
    __syncthreads();
    int lr = t >> 3, mc4 = (t & 7) * 4;
    float4 o = make_float4(tile[mc4 + 0][lr], tile[mc4 + 1][lr],
                           tile[mc4 + 2][lr], tile[mc4 + 3][lr]);
    *(float4*)&out[(size_t)b * SEQ * DM + (size_t)(l0 + lr) * DM + m0 + mc4] = o;
}

extern "C" void kernel_launch(void* const* d_in, const int* in_sizes, int n_in,
                              void* d_out, int out_size, void* d_ws, size_t ws_size,
                              hipStream_t stream) {
    const float* x     = (const float*)d_in[0];
    const float* Lam   = (const float*)d_in[1];
    const float* Bm    = (const float*)d_in[2];
    const float* Cm    = (const float*)d_in[3];
    const float* Dv    = (const float*)d_in[4];
    const float* logdt = (const float*)d_in[5];
    float* out = (float*)d_out;

    float*  ws   = (float*)d_ws;
    float*  xt   = ws;                                   // 4,194,304 floats (16 MB)
    float4* PQ   = (float4*)(ws + 4194304);              // 128*2048*2 float4 (8 MB)
    float*  K    = ws + 4194304 + 2097152;               // 524,288 floats (2 MB)
    float*  Psum = K + 524288;                           // 524,288 floats (2 MB)
    float*  GT   = Psum + 524288;                        // 16,384 floats

    hipLaunchKernelGGL(prep_G,         dim3(64),         dim3(NTP),  0, stream, Cm, Bm, GT);
    hipLaunchKernelGGL(prep_psum2,     dim3(256),        dim3(NTP),  0, stream, Lam, logdt, Psum);
    hipLaunchKernelGGL(prep_K2,        dim3(256),        dim3(NTP),  0, stream, GT, Psum, K);
    hipLaunchKernelGGL(fftK_PQ,        dim3(128),        dim3(NT),   0, stream, K, PQ);
    hipLaunchKernelGGL(transpose_xin,  dim3(128, 4, 8),  dim3(NT),   0, stream, x, xt);
    hipLaunchKernelGGL(conv16,         dim3(1024),       dim3(NT),   0, stream, xt, PQ, Dv);
    hipLaunchKernelGGL(transpose_yout, dim3(128, 4, 8),  dim3(NT),   0, stream, xt, out);
}